// Round 7
// baseline (508.942 us; speedup 1.0000x reference)
//
#include <hip/hip_runtime.h>
#include <math.h>

typedef _Float16 f16;
typedef _Float16 half8 __attribute__((ext_vector_type(8)));
typedef _Float16 hv2 __attribute__((ext_vector_type(2)));
typedef _Float16 hv4 __attribute__((ext_vector_type(4)));
typedef float f32x4 __attribute__((ext_vector_type(4)));
typedef __attribute__((address_space(1))) const unsigned int gu32;
typedef __attribute__((address_space(3))) unsigned int lu32;

#define BB 32
#define SS 1024
#define DD 512
#define NR (BB*SS)   // 32768
#define CH 16        // batches per S chunk (64 MiB fp32 chunk lives in d_out)
#define LTS 136      // LDS transpose stride (f16 units): 272B, 16B-aligned rows

// ---------- m97-style staging helpers (128B rows, 16B chunks, xor-swizzle row&7) ----------
__device__ __forceinline__ void stage128(const char* g, int ldb, char* lds,
                                         int wv, int ln) {
  #pragma unroll
  for (int r = 0; r < 4; r++) {
    int slot = r * 256 + wv * 64 + ln;
    int row = slot >> 3, cp = slot & 7;
    int c = cp ^ (row & 7);
    const char* gp = g + (size_t)row * ldb + (c << 4);
    char* lp = lds + ((slot - ln) << 4);
    __builtin_amdgcn_global_load_lds((gu32*)gp, (lu32*)lp, 16, 0, 0);
  }
}

__device__ __forceinline__ void stage64(const char* g, int ldb, char* lds,
                                        int wv, int ln) {
  #pragma unroll
  for (int r = 0; r < 2; r++) {
    int slot = r * 256 + wv * 64 + ln;
    int row = slot >> 3, cp = slot & 7;
    int c = cp ^ (row & 7);
    const char* gp = g + (size_t)row * ldb + (c << 4);
    char* lp = lds + ((slot - ln) << 4);
    __builtin_amdgcn_global_load_lds((gu32*)gp, (lu32*)lp, 16, 0, 0);
  }
}

__device__ __forceinline__ half8 frag_ld(const char* lds, int row, int kc) {
  return *(const half8*)(lds + row * 128 + ((kc ^ (row & 7)) << 4));
}

__device__ __forceinline__ f32x4 MF(half8 a, half8 b, f32x4 c) {
  return __builtin_amdgcn_mfma_f32_16x16x32_f16(a, b, c, 0, 0, 0);
}

// ---------------- K1: embed+LN  |  Gt = Wk·Wq^T (fp32, split out)  |  Wv transpose ----
__global__ __launch_bounds__(256) void k_prep(
    const int* __restrict__ inp, const float* __restrict__ wemb,
    const float* __restrict__ pemb, const float* __restrict__ gamma,
    const float* __restrict__ beta, f16* __restrict__ Xhi, f16* __restrict__ Xlo,
    const float* __restrict__ Wq, const float* __restrict__ Wk,
    const float* __restrict__ Wv, f16* __restrict__ Gthi, f16* __restrict__ Gtlo,
    f16* __restrict__ Wvt)
{
  int bid = blockIdx.x;
  int tid = threadIdx.x;
  __shared__ float red[10];
  __shared__ __align__(16) char pool[34816];   // As/Bs (G) or Lt (transpose)
  if (bid >= NR + 64) {          // ---- Wv transpose + f16, 64x64 LDS tiles ----
    float (*Lt)[65] = (float(*)[65])pool;
    int tt = bid - (NR + 64);    // 0..63
    int tr = tt >> 3, tc = tt & 7;
    int rr = tid >> 4;
    int c4 = (tid & 15) * 4;
    #pragma unroll
    for (int p = 0; p < 4; p++) {
      float4 v = *(const float4*)&Wv[(size_t)(tr * 64 + p * 16 + rr) * DD + tc * 64 + c4];
      Lt[p * 16 + rr][c4 + 0] = v.x; Lt[p * 16 + rr][c4 + 1] = v.y;
      Lt[p * 16 + rr][c4 + 2] = v.z; Lt[p * 16 + rr][c4 + 3] = v.w;
    }
    __syncthreads();
    #pragma unroll
    for (int p = 0; p < 4; p++) {
      int dl = p * 16 + rr;
      float v0 = Lt[c4 + 0][dl], v1 = Lt[c4 + 1][dl];
      float v2 = Lt[c4 + 2][dl], v3 = Lt[c4 + 3][dl];
      size_t o = (size_t)(tc * 64 + dl) * DD + tr * 64 + c4;
      *(hv4*)&Wvt[o] = (hv4){(f16)v0, (f16)v1, (f16)v2, (f16)v3};
    }
    return;
  }
  if (bid >= NR) {               // ---- Gt[e][d] = sum_h Wk[e][h]*Wq[d][h] ----
    float (*As)[68] = (float(*)[68])pool;                // [h][e] transposed
    float (*Bs)[68] = (float(*)[68])(pool + 17408);      // [h][d]
    int g2 = bid - NR;
    int e0 = (g2 >> 3) * 64;
    int d0 = (g2 & 7) * 64;
    int te = tid >> 4, td = tid & 15;
    float acc[4][4] = {{0}};
    for (int h0 = 0; h0 < DD; h0 += 64) {
      __syncthreads();
      #pragma unroll
      for (int p = 0; p < 4; p++) {
        int slot = tid + p * 256;
        int r = slot >> 4, c4 = (slot & 15) * 4;
        float4 a = *(const float4*)&Wk[(size_t)(e0 + r) * DD + h0 + c4];
        float4 b = *(const float4*)&Wq[(size_t)(d0 + r) * DD + h0 + c4];
        As[c4 + 0][r] = a.x; As[c4 + 1][r] = a.y; As[c4 + 2][r] = a.z; As[c4 + 3][r] = a.w;
        Bs[c4 + 0][r] = b.x; Bs[c4 + 1][r] = b.y; Bs[c4 + 2][r] = b.z; Bs[c4 + 3][r] = b.w;
      }
      __syncthreads();
      #pragma unroll 8
      for (int h = 0; h < 64; h++) {
        float4 a4 = *(float4*)&As[h][te * 4];
        float4 b4 = *(float4*)&Bs[h][td * 4];
        float a[4] = {a4.x, a4.y, a4.z, a4.w};
        float b[4] = {b4.x, b4.y, b4.z, b4.w};
        #pragma unroll
        for (int i = 0; i < 4; i++)
          #pragma unroll
          for (int j = 0; j < 4; j++) acc[i][j] = fmaf(a[i], b[j], acc[i][j]);
      }
    }
    #pragma unroll
    for (int i = 0; i < 4; i++)
      #pragma unroll
      for (int j = 0; j < 4; j++) {
        float v = acc[i][j];
        f16 h = (f16)v;
        size_t o = (size_t)(e0 + te * 4 + i) * DD + d0 + td * 4 + j;
        Gthi[o] = h; Gtlo[o] = (f16)(v - (float)h);
      }
    return;
  }
  // ---- embedding + layernorm -> split fp16 X ----
  int row = bid;
  int s   = row & (SS - 1);
  int tok = inp[row];
  float2 w = ((const float2*)(wemb + (size_t)tok * DD))[tid];
  float2 p = ((const float2*)(pemb + (size_t)s   * DD))[tid];
  float ex = w.x + p.x, ey = w.y + p.y;
  float sum = ex + ey, ssq = ex*ex + ey*ey;
  #pragma unroll
  for (int off = 32; off > 0; off >>= 1) {
    sum += __shfl_down(sum, off, 64);
    ssq += __shfl_down(ssq, off, 64);
  }
  int wv = tid >> 6, ln = tid & 63;
  if (ln == 0) { red[wv] = sum; red[4 + wv] = ssq; }
  __syncthreads();
  if (tid == 0) {
    float s4 = red[0] + red[1] + red[2] + red[3];
    float q4 = red[4] + red[5] + red[6] + red[7];
    float mean = s4 * (1.0f / DD);
    float var  = q4 * (1.0f / DD) - mean * mean;
    red[8] = mean; red[9] = rsqrtf(var + 1e-5f);
  }
  __syncthreads();
  float mean = red[8], rstd = red[9];
  float2 g  = ((const float2*)gamma)[tid];
  float2 bt = ((const float2*)beta)[tid];
  float ox = (ex - mean) * rstd * g.x + bt.x;
  float oy = (ey - mean) * rstd * g.y + bt.y;
  f16 hx = (f16)ox, hy = (f16)oy;
  f16 lx = (f16)(ox - (float)hx), ly = (f16)(oy - (float)hy);
  ((hv2*)(Xhi + (size_t)row * DD))[tid] = (hv2){hx, hy};
  ((hv2*)(Xlo + (size_t)row * DD))[tid] = (hv2){lx, ly};
}

// ---------------- K2: T = X·G (3-term split)  +  V = X·Wv (plain) -> Vt ----------------
__global__ __launch_bounds__(256, 2) void k_projtv(
    const f16* __restrict__ Xhi, const f16* __restrict__ Xlo,
    const f16* __restrict__ Gthi, const f16* __restrict__ Gtlo,
    const f16* __restrict__ Wvt,
    f16* __restrict__ Thi, f16* __restrict__ Tlo, f16* __restrict__ Vt)
{
  __shared__ __align__(16) char pool[65536];
  char* Ah = pool;
  char* Al = pool + 16384;
  char* Bh = pool + 32768;
  char* Bl = pool + 49152;
  f16* LT = (f16*)pool;                 // 128 x LTS f16 = 34816 B, reused post-loop
  int tid = threadIdx.x, wv = tid >> 6, ln = tid & 63;
  int mw = wv & 1, nw = wv >> 1;
  int n0 = blockIdx.x * 128;   // output col (e for T, d for V)
  int m0 = blockIdx.y * 128;   // s
  f32x4 at[4][4], av[4][4];
  #pragma unroll
  for (int i = 0; i < 4; i++)
    #pragma unroll
    for (int j = 0; j < 4; j++) { at[i][j] = (f32x4)(0.0f); av[i][j] = (f32x4)(0.0f); }
  int quad = ln >> 4, l15 = ln & 15;
  for (int k0 = 0; k0 < DD; k0 += 64) {
    __syncthreads();
    stage128((const char*)(Xhi  + (size_t)m0 * DD + k0), 1024, Ah, wv, ln);
    stage128((const char*)(Xlo  + (size_t)m0 * DD + k0), 1024, Al, wv, ln);
    stage128((const char*)(Gthi + (size_t)n0 * DD + k0), 1024, Bh, wv, ln);
    stage128((const char*)(Gtlo + (size_t)n0 * DD + k0), 1024, Bl, wv, ln);
    __syncthreads();
    #pragma unroll
    for (int ks = 0; ks < 2; ks++) {
      int kc = ks * 4 + quad;
      half8 ah[4], al[4], bh[4], bl[4];
      #pragma unroll
      for (int t = 0; t < 4; t++) {
        ah[t] = frag_ld(Ah, mw * 64 + t * 16 + l15, kc);
        al[t] = frag_ld(Al, mw * 64 + t * 16 + l15, kc);
        bh[t] = frag_ld(Bh, nw * 64 + t * 16 + l15, kc);
        bl[t] = frag_ld(Bl, nw * 64 + t * 16 + l15, kc);
      }
      #pragma unroll
      for (int i = 0; i < 4; i++)
        #pragma unroll
        for (int j = 0; j < 4; j++) {
          at[i][j] = MF(ah[i], bh[j], at[i][j]);
          at[i][j] = MF(ah[i], bl[j], at[i][j]);
          at[i][j] = MF(al[i], bh[j], at[i][j]);
        }
    }
    __syncthreads();
    stage128((const char*)(Wvt + (size_t)n0 * DD + k0), 1024, Bh, wv, ln);
    __syncthreads();
    #pragma unroll
    for (int ks = 0; ks < 2; ks++) {
      int kc = ks * 4 + quad;
      half8 ah[4], bv[4];
      #pragma unroll
      for (int t = 0; t < 4; t++) {
        ah[t] = frag_ld(Ah, mw * 64 + t * 16 + l15, kc);
        bv[t] = frag_ld(Bh, nw * 64 + t * 16 + l15, kc);
      }
      #pragma unroll
      for (int i = 0; i < 4; i++)
        #pragma unroll
        for (int j = 0; j < 4; j++) av[i][j] = MF(ah[i], bv[j], av[i][j]);
    }
  }
  // ---- T epilogue: split-f16 store ----
  #pragma unroll
  for (int i = 0; i < 4; i++)
    #pragma unroll
    for (int j = 0; j < 4; j++)
      #pragma unroll
      for (int rg = 0; rg < 4; rg++) {
        int gm = m0 + mw * 64 + i * 16 + quad * 4 + rg;
        int gn = n0 + nw * 64 + j * 16 + l15;
        size_t o = (size_t)gm * DD + gn;
        float v = at[i][j][rg];
        f16 h = (f16)v;
        Thi[o] = h; Tlo[o] = (f16)(v - (float)h);
      }
  // ---- V epilogue: LDS transpose -> Vt[d][s] coalesced ----
  __syncthreads();
  #pragma unroll
  for (int i = 0; i < 4; i++)
    #pragma unroll
    for (int j = 0; j < 4; j++) {
      int dl = nw * 64 + j * 16 + l15;
      int sb = mw * 64 + i * 16 + quad * 4;
      *(hv4*)&LT[dl * LTS + sb] =
          (hv4){(f16)av[i][j][0], (f16)av[i][j][1], (f16)av[i][j][2], (f16)av[i][j][3]};
    }
  __syncthreads();
  #pragma unroll
  for (int g = 0; g < 8; g++) {
    int dl = wv * 32 + g * 4 + (ln >> 4);
    int s8 = (ln & 15) * 8;
    half8 v = *(half8*)&LT[dl * LTS + s8];
    *(half8*)&Vt[(size_t)(n0 + dl) * NR + m0 + s8] = v;
  }
}

// ---------------- K3: S = T X^T / sqrt(D) — 64q x 256k blocks, 16-batch chunk -------
__global__ __launch_bounds__(256, 2) void k_st(
    const f16* __restrict__ Thi, const f16* __restrict__ Tlo,
    const f16* __restrict__ Xhi, const f16* __restrict__ Xlo,
    float* __restrict__ S, int chunk)
{
  __shared__ __align__(16) char Ah[8192], Al[8192], Bh[16384], Bl[16384];
  int tid = threadIdx.x, wv = tid >> 6, ln = tid & 63;
  int n0 = blockIdx.x * 256;          // key base
  int m0 = blockIdx.y * 64;           // query base
  int z  = blockIdx.z;                // batch within chunk (0..15)
  size_t brow = ((size_t)chunk * CH + z) * SS;
  f32x4 acc[2][4][2];
  #pragma unroll
  for (int p = 0; p < 2; p++)
    #pragma unroll
    for (int i = 0; i < 4; i++)
      #pragma unroll
      for (int j = 0; j < 2; j++) acc[p][i][j] = (f32x4)(0.0f);
  int quad = ln >> 4, l15 = ln & 15;
  for (int k0 = 0; k0 < DD; k0 += 64) {
    __syncthreads();
    stage64 ((const char*)(Thi + (brow + m0) * DD + k0), 1024, Ah, wv, ln);
    stage64 ((const char*)(Tlo + (brow + m0) * DD + k0), 1024, Al, wv, ln);
    stage128((const char*)(Xhi + (brow + n0) * DD + k0), 1024, Bh, wv, ln);
    stage128((const char*)(Xlo + (brow + n0) * DD + k0), 1024, Bl, wv, ln);
    __syncthreads();
    #pragma unroll
    for (int ks = 0; ks < 2; ks++) {
      int kc = ks * 4 + quad;
      half8 ah[4], al[4], bh[2], bl[2];
      #pragma unroll
      for (int t = 0; t < 4; t++) {
        ah[t] = frag_ld(Ah, t * 16 + l15, kc);
        al[t] = frag_ld(Al, t * 16 + l15, kc);
      }
      #pragma unroll
      for (int t = 0; t < 2; t++) {
        bh[t] = frag_ld(Bh, wv * 32 + t * 16 + l15, kc);
        bl[t] = frag_ld(Bl, wv * 32 + t * 16 + l15, kc);
      }
      #pragma unroll
      for (int i = 0; i < 4; i++)
        #pragma unroll
        for (int j = 0; j < 2; j++) {
          acc[0][i][j] = MF(ah[i], bh[j], acc[0][i][j]);
          acc[0][i][j] = MF(ah[i], bl[j], acc[0][i][j]);
          acc[0][i][j] = MF(al[i], bh[j], acc[0][i][j]);
        }
    }
    __syncthreads();
    stage128((const char*)(Xhi + (brow + n0 + 128) * DD + k0), 1024, Bh, wv, ln);
    stage128((const char*)(Xlo + (brow + n0 + 128) * DD + k0), 1024, Bl, wv, ln);
    __syncthreads();
    #pragma unroll
    for (int ks = 0; ks < 2; ks++) {
      int kc = ks * 4 + quad;
      half8 ah[4], al[4], bh[2], bl[2];
      #pragma unroll
      for (int t = 0; t < 4; t++) {
        ah[t] = frag_ld(Ah, t * 16 + l15, kc);
        al[t] = frag_ld(Al, t * 16 + l15, kc);
      }
      #pragma unroll
      for (int t = 0; t < 2; t++) {
        bh[t] = frag_ld(Bh, wv * 32 + t * 16 + l15, kc);
        bl[t] = frag_ld(Bl, wv * 32 + t * 16 + l15, kc);
      }
      #pragma unroll
      for (int i = 0; i < 4; i++)
        #pragma unroll
        for (int j = 0; j < 2; j++) {
          acc[1][i][j] = MF(ah[i], bh[j], acc[1][i][j]);
          acc[1][i][j] = MF(ah[i], bl[j], acc[1][i][j]);
          acc[1][i][j] = MF(al[i], bh[j], acc[1][i][j]);
        }
    }
  }
  const float scale = 0.044194173824159216f;   // 1/sqrt(512)
  #pragma unroll
  for (int p = 0; p < 2; p++)
    #pragma unroll
    for (int i = 0; i < 4; i++)
      #pragma unroll
      for (int j = 0; j < 2; j++)
        #pragma unroll
        for (int rg = 0; rg < 4; rg++) {
          int gm = m0 + i * 16 + quad * 4 + rg;
          int gn = n0 + p * 128 + wv * 32 + j * 16 + l15;
          S[((size_t)z * SS + gm) * SS + gn] = acc[p][i][j][rg] * scale;
        }
}

// ---------------- K4: row softmax S(fp32, d_out) -> P(fp16) ----------------
__global__ __launch_bounds__(256) void k_sm(
    const float* __restrict__ S, f16* __restrict__ P)
{
  int rc = blockIdx.x;                 // row within chunk, 0..16383
  int tid = threadIdx.x;
  const float* row = S + (size_t)rc * SS;
  float4 v = ((const float4*)row)[tid];
  float mx = fmaxf(fmaxf(v.x, v.y), fmaxf(v.z, v.w));
  #pragma unroll
  for (int off = 32; off > 0; off >>= 1) mx = fmaxf(mx, __shfl_xor(mx, off, 64));
  __shared__ float red[10];
  int wv = tid >> 6;
  if ((tid & 63) == 0) red[wv] = mx;
  __syncthreads();
  if (tid == 0) red[8] = fmaxf(fmaxf(red[0], red[1]), fmaxf(red[2], red[3]));
  __syncthreads();
  mx = red[8];
  float e0 = __expf(v.x - mx), e1 = __expf(v.y - mx);
  float e2 = __expf(v.z - mx), e3 = __expf(v.w - mx);
  float sm = e0 + e1 + e2 + e3;
  #pragma unroll
  for (int off = 32; off > 0; off >>= 1) sm += __shfl_xor(sm, off, 64);
  if ((tid & 63) == 0) red[4 + wv] = sm;
  __syncthreads();
  if (tid == 0) red[9] = red[4] + red[5] + red[6] + red[7];
  __syncthreads();
  float inv = 1.0f / red[9];
  ((hv4*)(P + (size_t)rc * SS))[tid] =
      (hv4){(f16)(e0 * inv), (f16)(e1 * inv), (f16)(e2 * inv), (f16)(e3 * inv)};
}

// ---------------- K5: O = P V  (plain fp16 MFMA) ----------------
__global__ __launch_bounds__(256, 2) void k_pv(
    const f16* __restrict__ P0, const f16* __restrict__ P1,
    const f16* __restrict__ Vt, float* __restrict__ O)
{
  __shared__ __align__(16) char Ah[16384], Bh[16384];
  int tid = threadIdx.x, wv = tid >> 6, ln = tid & 63;
  int mw = wv & 1, nw = wv >> 1;
  int n0 = blockIdx.x * 128;          // d_out
  int m0 = blockIdx.y * 128;          // query (within batch)
  int b  = blockIdx.z;
  const f16* Pbase = (b < CH) ? P0 : P1;
  const char* Pt = (const char*)(Pbase + ((size_t)((b & (CH - 1)) * SS + m0)) * SS);
  f32x4 acc[4][4];
  #pragma unroll
  for (int i = 0; i < 4; i++)
    #pragma unroll
    for (int j = 0; j < 4; j++) acc[i][j] = (f32x4)(0.0f);
  for (int k0 = 0; k0 < SS; k0 += 64) {
    __syncthreads();
    stage128(Pt + k0 * 2, 2048, Ah, wv, ln);
    stage128((const char*)(Vt + (size_t)n0 * NR + (size_t)b * SS + k0), NR * 2, Bh, wv, ln);
    __syncthreads();
    int quad = ln >> 4, l15 = ln & 15;
    #pragma unroll
    for (int ks = 0; ks < 2; ks++) {
      int kc = ks * 4 + quad;
      half8 a[4], bf[4];
      #pragma unroll
      for (int t = 0; t < 4; t++) {
        a[t]  = frag_ld(Ah, mw * 64 + t * 16 + l15, kc);
        bf[t] = frag_ld(Bh, nw * 64 + t * 16 + l15, kc);
      }
      #pragma unroll
      for (int i = 0; i < 4; i++)
        #pragma unroll
        for (int j = 0; j < 4; j++) acc[i][j] = MF(a[i], bf[j], acc[i][j]);
    }
  }
  int quad = ln >> 4, l15 = ln & 15;
  #pragma unroll
  for (int i = 0; i < 4; i++)
    #pragma unroll
    for (int j = 0; j < 4; j++)
      #pragma unroll
      for (int rg = 0; rg < 4; rg++) {
        int gm = m0 + mw * 64 + i * 16 + quad * 4 + rg;
        int gn = n0 + nw * 64 + j * 16 + l15;
        O[((size_t)b * SS + gm) * DD + gn] = acc[i][j][rg];
      }
}

extern "C" void kernel_launch(void* const* d_in, const int* in_sizes, int n_in,
                              void* d_out, int out_size, void* d_ws, size_t ws_size,
                              hipStream_t stream) {
  const int*   inp   = (const int*)d_in[0];
  const float* wemb  = (const float*)d_in[1];
  const float* pemb  = (const float*)d_in[2];
  const float* gamma = (const float*)d_in[3];
  const float* beta  = (const float*)d_in[4];
  const float* Wk    = (const float*)d_in[5];
  const float* Wq    = (const float*)d_in[6];
  const float* Wv    = (const float*)d_in[7];

  // ws (192 MiB): [Xhi 32M][Xlo 32M][Thi 32M][Tlo 32M][Vt 32M][P0 32M]
  // P1 (32M) overlays Thi (dead after st chunk1). S chunks (64 MiB fp32) -> d_out.
  char* ws = (char*)d_ws;
  f16* Xhi = (f16*)ws;
  f16* Xlo = (f16*)(ws + ((size_t)32 << 20));
  f16* Thi = (f16*)(ws + ((size_t)64 << 20));
  f16* Tlo = (f16*)(ws + ((size_t)96 << 20));
  f16* Vt  = (f16*)(ws + ((size_t)128 << 20));
  f16* P0  = (f16*)(ws + ((size_t)160 << 20));
  f16* P1  = (f16*)(ws + ((size_t)64 << 20));   // over Thi

  f16* Gthi = (f16*)d_out;                      // parked in d_out head; consumed
  f16* Gtlo = Gthi + (size_t)DD * DD;           // by projtv before st writes S there
  f16* Wvt  = Gtlo + (size_t)DD * DD;

  float* Sb = (float*)d_out;

  k_prep<<<NR + 128, 256, 0, stream>>>(inp, wemb, pemb, gamma, beta, Xhi, Xlo,
                                       Wq, Wk, Wv, Gthi, Gtlo, Wvt);
  k_projtv<<<dim3(DD / 128, NR / 128), 256, 0, stream>>>(
      Xhi, Xlo, Gthi, Gtlo, Wvt, Thi, Tlo, Vt);
  for (int c = 0; c < 2; c++) {
    k_st<<<dim3(SS / 256, SS / 64, CH), 256, 0, stream>>>(Thi, Tlo, Xhi, Xlo, Sb, c);
    k_sm<<<CH * SS, 256, 0, stream>>>(Sb, c == 0 ? P0 : P1);
  }
  k_pv<<<dim3(DD / 128, SS / 128, BB), 256, 0, stream>>>(P0, P1, Vt, (float*)d_out);
}